// Round 7
// baseline (816.674 us; speedup 1.0000x reference)
//
#include <hip/hip_runtime.h>
#include <hip/hip_bf16.h>
#include <cstdint>
#include <cstddef>

#define NTOK 16384   // B*L = 4*4096
#define DDIM 1024
#define NEXP 8
#define CPAD 32      // counter padding: 32 ints = 128B per counter

typedef __attribute__((ext_vector_type(8))) short bf16x8;
typedef __attribute__((ext_vector_type(4))) float f32x4;

__device__ __forceinline__ unsigned short f2bf(float f) {
  union { float f; unsigned u; } c; c.f = f;
  unsigned r = (c.u + 0x7FFFu + ((c.u >> 16) & 1u)) >> 16;  // RNE
  return (unsigned short)r;
}

__device__ __forceinline__ float gelu_exact(float v) {
  return 0.5f * v * (1.0f + erff(v * 0.70710678118654752440f));
}

// direct global->LDS async copy, 16B per lane. LDS dest must be linear
// (wave-uniform base + lane*16); source address is per-lane.
#define GL2LDS(gp, lp) __builtin_amdgcn_global_load_lds( \
    (__attribute__((address_space(1))) void*)(gp),       \
    (__attribute__((address_space(3))) void*)(lp), 16, 0, 0)

// ---------------- cast fp32 -> bf16, 4 elems/thread (weights) ----------------
__global__ void cast_k(const float* __restrict__ src, unsigned short* __restrict__ dst, int n4) {
  int i = blockIdx.x * blockDim.x + threadIdx.x;
  if (i >= n4) return;
  float4 a = ((const float4*)src)[i];
  union { unsigned short s[4]; uint2 v; } o;
  o.s[0] = f2bf(a.x); o.s[1] = f2bf(a.y); o.s[2] = f2bf(a.z); o.s[3] = f2bf(a.w);
  ((uint2*)dst)[i] = o.v;
}

// ---------------- fused x-cast + router: one block per token, NO atomics ----------------
__global__ __launch_bounds__(256)
void castx_router_k(const float* __restrict__ x, const float* __restrict__ Wr,
                    unsigned short* __restrict__ xb, int* __restrict__ tokE,
                    float2* __restrict__ tokW) {
  const int t = blockIdx.x;
  const int tid = threadIdx.x;
  const int w = tid >> 6, lane = tid & 63;

  float4 xv = ((const float4*)x)[(size_t)t * 256 + tid];   // coalesced 16B/thread
  union { unsigned short s[4]; uint2 v; } o;
  o.s[0] = f2bf(xv.x); o.s[1] = f2bf(xv.y); o.s[2] = f2bf(xv.z); o.s[3] = f2bf(xv.w);
  ((uint2*)xb)[(size_t)t * 256 + tid] = o.v;

  const float4* Wr4 = (const float4*)Wr;                   // 32KB, L1-resident
  float p[NEXP];
#pragma unroll
  for (int e = 0; e < NEXP; ++e) {
    float4 wv = Wr4[e * 256 + tid];
    p[e] = xv.x * wv.x + xv.y * wv.y + xv.z * wv.z + xv.w * wv.w;
  }
#pragma unroll
  for (int e = 0; e < NEXP; ++e) {
    float v = p[e];
#pragma unroll
    for (int off = 32; off >= 1; off >>= 1) v += __shfl_xor(v, off, 64);
    p[e] = v;
  }
  __shared__ float red[4][NEXP];
  if (lane == 0) {
#pragma unroll
    for (int e = 0; e < NEXP; ++e) red[w][e] = p[e];
  }
  __syncthreads();
  if (tid == 0) {
    float s[NEXP];
#pragma unroll
    for (int e = 0; e < NEXP; ++e) s[e] = red[0][e] + red[1][e] + red[2][e] + red[3][e];
    int e1 = 0; float m1 = s[0];
#pragma unroll
    for (int e = 1; e < NEXP; ++e) if (s[e] > m1) { m1 = s[e]; e1 = e; }
    int e2 = -1; float m2 = -3.4e38f;
#pragma unroll
    for (int e = 0; e < NEXP; ++e) {
      if (e == e1) continue;
      if (s[e] > m2) { m2 = s[e]; e2 = e; }
    }
    float dd = expf(m2 - m1);                 // renormalized top-2 softmax
    tokE[t] = e1 | (e2 << 8);
    tokW[t] = make_float2(1.f / (1.f + dd), dd / (1.f + dd));
  }
}

// ---------------- histogram: ballot-aggregated, 8 atomics/block on padded lines ----------------
__global__ __launch_bounds__(256)
void hist_k(const int* __restrict__ tokE, int* __restrict__ cnt) {
  const int t = blockIdx.x * blockDim.x + threadIdx.x;
  const int w = threadIdx.x >> 6, lane = threadIdx.x & 63;
  const int pk = tokE[t];
  const int e1 = pk & 0xFF, e2 = (pk >> 8) & 0xFF;
  __shared__ int h[4][NEXP];
#pragma unroll
  for (int e = 0; e < NEXP; ++e) {
    int c = (int)__popcll(__ballot(e1 == e)) + (int)__popcll(__ballot(e2 == e));
    if (lane == 0) h[w][e] = c;
  }
  __syncthreads();
  if (threadIdx.x < NEXP) {
    int tot = h[0][threadIdx.x] + h[1][threadIdx.x] + h[2][threadIdx.x] + h[3][threadIdx.x];
    atomicAdd(&cnt[threadIdx.x * CPAD], tot);
  }
}

// ---------------- exclusive prefix over 8 padded counts ----------------
__global__ void offsets_k(const int* __restrict__ cnt, int* __restrict__ off) {
  if (threadIdx.x == 0) {
    int a = 0;
    for (int e = 0; e < NEXP; ++e) { off[e] = a; a += cnt[e * CPAD]; }
  }
}

// wave-aggregated bucket slot allocation on PADDED counters
__device__ __forceinline__ int bucket_slot(int* cur, int e_sel) {
  int lane = threadIdx.x & 63;
  int slot = 0;
#pragma unroll
  for (int e = 0; e < NEXP; ++e) {
    unsigned long long m = __ballot(e_sel == e);
    if (e_sel == e) {
      unsigned long long below = m & ((1ull << lane) - 1ull);
      int leader = __ffsll((long long)m) - 1;
      int base = 0;
      if (lane == leader) base = atomicAdd(&cur[e * CPAD], (int)__popcll(m));
      base = __shfl(base, leader, 64);
      slot = base + (int)__popcll(below);
    }
  }
  return slot;
}

__global__ __launch_bounds__(256)
void place_k(const int* __restrict__ tokE, const float2* __restrict__ tokW,
             const int* __restrict__ off, int* __restrict__ cur,
             int* __restrict__ asgT, float* __restrict__ asgW) {
  int t = blockIdx.x * blockDim.x + threadIdx.x;
  if (t >= NTOK) return;
  int pk = tokE[t];
  float2 w = tokW[t];
  int e1 = pk & 0xFF, e2 = (pk >> 8) & 0xFF;
  int p1 = off[e1] + bucket_slot(cur, e1);
  asgT[p1] = t; asgW[p1] = w.x;
  int p2 = off[e2] + bucket_slot(cur, e2);
  asgT[p2] = t; asgW[p2] = w.y;
}

// ============ 256x256 tile, BK=64, 8 waves (2Mx4N), 8-phase-style schedule ============
// LDS fragment-major, per K-tile per matrix: 32 sub-blocks (g 0..15, ks 0..1) of 1KB;
// sub(g,ks) holds rows/cols g*16..g*16+15, k-slice ks*32..+31, element (r,kc) at
// lane(kc*16+r)*16B -> gl2lds linear dest AND conflict-free ds_read_b128 (0 conflicts
// measured R4-R6). Double-buffered: 2 x 32KB x {A,B} = 128KB.
// Schedule per K-tile t (buffer b=t&1), 4 phases x 16 MFMA:
//   gate: sched_barrier; vmcnt(0) [drains t's stages, ISSUED one full tile ago ->
//         provably landed, free]; s_barrier; sched_barrier
//   ph0:  12 ds_read (bv all 8 + af i0,i1) ; ISSUE all 8 gl2lds of tile t+1 into b^1
//         [b^1 last read at t-1, sealed by the two barriers since] ; barrier;
//         lgkmcnt(0)+sched_barrier; setprio(1); 16 MFMA (i0-1 x j0-3 x ks0-1); setprio(0); barrier
//   ph1-3: 4 ds_read (af i2p,2p+1); barrier; lgkm+schb; setprio; 16 MFMA; setprio; barrier
// Race-free: no stage ever targets the buffer being read; the vmcnt gate is 4 phases
// downstream of its issue (m218's counted-vmcnt mechanism without counted N).

#define GEMM_CORE(EPILOG_PRE, SRC_A_INIT)                                               \
  const int e = blockIdx.z;                                                             \
  const int cnt = cntp[e * CPAD];                                                       \
  const int m0 = blockIdx.x * 256;                                                      \
  if (m0 >= cnt) return;                                                                \
  const int off = offp[e];                                                              \
  const int n0 = blockIdx.y * 256;                                                      \
  __shared__ __align__(16) unsigned short As[2][16384];                                 \
  __shared__ __align__(16) unsigned short Bs[2][16384];                                 \
  const int tid = threadIdx.x;                                                          \
  const int w = tid >> 6, lane = tid & 63;                                              \
  const int r = lane & 15, kc = lane >> 4;                                              \
  const int wr = w >> 2, wc = w & 3;                                                    \
  const unsigned short* srcA[2];                                                        \
  const unsigned short* srcB[2];                                                        \
  _Pragma("unroll")                                                                     \
  for (int i = 0; i < 2; ++i) {                                                         \
    int g = 2 * w + i;                                                                  \
    int rowt = m0 + g * 16 + r;                                                         \
    int rowc = (rowt < cnt) ? rowt : m0;                                                \
    SRC_A_INIT;                                                                         \
    int coln = n0 + g * 16 + r;                                                         \
    srcB[i] = Bsrc + (size_t)e * DDIM * DDIM + (size_t)coln * DDIM + kc * 8;            \
  }                                                                                     \
  f32x4 acc[8][4];                                                                      \
  _Pragma("unroll")                                                                     \
  for (int i = 0; i < 8; ++i)                                                           \
    _Pragma("unroll")                                                                   \
    for (int j = 0; j < 4; ++j) acc[i][j] = (f32x4){0.f, 0.f, 0.f, 0.f};                \
  auto stage = [&](int buf, int kt) {                                                   \
    _Pragma("unroll")                                                                   \
    for (int i = 0; i < 2; ++i) {                                                       \
      int g = 2 * w + i;                                                                \
      _Pragma("unroll")                                                                 \
      for (int ks = 0; ks < 2; ++ks) {                                                  \
        GL2LDS(srcA[i] + kt * 64 + ks * 32, &As[buf][(g * 2 + ks) * 512 + lane * 8]);   \
        GL2LDS(srcB[i] + kt * 64 + ks * 32, &Bs[buf][(g * 2 + ks) * 512 + lane * 8]);   \
      }                                                                                 \
    }                                                                                   \
  };                                                                                    \
  stage(0, 0);                                                                          \
  for (int t = 0; t < 16; ++t) {                                                        \
    const int b = t & 1;                                                                \
    __builtin_amdgcn_sched_barrier(0);                                                  \
    asm volatile("s_waitcnt vmcnt(0)" ::: "memory");                                    \
    __builtin_amdgcn_s_barrier();                                                       \
    __builtin_amdgcn_sched_barrier(0);                                                  \
    bf16x8 bv[4][2], af[2][2];                                                          \
    _Pragma("unroll")                                                                   \
    for (int j = 0; j < 4; ++j)                                                         \
      _Pragma("unroll")                                                                 \
      for (int ks = 0; ks < 2; ++ks)                                                    \
        bv[j][ks] = *(const bf16x8*)&Bs[b][((wc * 4 + j) * 2 + ks) * 512 + lane * 8];   \
    _Pragma("unroll")                                                                   \
    for (int i = 0; i < 2; ++i)                                                         \
      _Pragma("unroll")                                                                 \
      for (int ks = 0; ks < 2; ++ks)                                                    \
        af[i][ks] = *(const bf16x8*)&As[b][((wr * 8 + i) * 2 + ks) * 512 + lane * 8];   \
    if (t + 1 < 16) stage(b ^ 1, t + 1);                                                \
    __builtin_amdgcn_s_barrier();                                                       \
    asm volatile("s_waitcnt lgkmcnt(0)" ::: "memory");                                  \
    __builtin_amdgcn_sched_barrier(0);                                                  \
    __builtin_amdgcn_s_setprio(1);                                                      \
    _Pragma("unroll")                                                                   \
    for (int ks = 0; ks < 2; ++ks)                                                      \
      _Pragma("unroll")                                                                 \
      for (int i = 0; i < 2; ++i)                                                       \
        _Pragma("unroll")                                                               \
        for (int j = 0; j < 4; ++j)                                                     \
          acc[i][j] = __builtin_amdgcn_mfma_f32_16x16x32_bf16(af[i][ks], bv[j][ks],     \
                                                              acc[i][j], 0, 0, 0);      \
    __builtin_amdgcn_s_setprio(0);                                                      \
    __builtin_amdgcn_s_barrier();                                                       \
    _Pragma("unroll")                                                                   \
    for (int p = 1; p < 4; ++p) {                                                       \
      _Pragma("unroll")                                                                 \
      for (int i = 0; i < 2; ++i)                                                       \
        _Pragma("unroll")                                                               \
        for (int ks = 0; ks < 2; ++ks)                                                  \
          af[i][ks] = *(const bf16x8*)&As[b][((wr * 8 + 2 * p + i) * 2 + ks) * 512 +    \
                                             lane * 8];                                 \
      __builtin_amdgcn_s_barrier();                                                     \
      asm volatile("s_waitcnt lgkmcnt(0)" ::: "memory");                                \
      __builtin_amdgcn_sched_barrier(0);                                                \
      __builtin_amdgcn_s_setprio(1);                                                    \
      _Pragma("unroll")                                                                 \
      for (int ks = 0; ks < 2; ++ks)                                                    \
        _Pragma("unroll")                                                               \
        for (int i = 0; i < 2; ++i)                                                     \
          _Pragma("unroll")                                                             \
          for (int j = 0; j < 4; ++j)                                                   \
            acc[2 * p + i][j] = __builtin_amdgcn_mfma_f32_16x16x32_bf16(                \
                af[i][ks], bv[j][ks], acc[2 * p + i][j], 0, 0, 0);                      \
      __builtin_amdgcn_s_setprio(0);                                                    \
      __builtin_amdgcn_s_barrier();                                                     \
    }                                                                                   \
  }                                                                                     \
  EPILOG_PRE

// ---------------- GEMM1: h = gelu(gather(x) @ W1[e]^T + b1[e]) ----------------
__global__ __launch_bounds__(512, 2)
void gemm1_k(const unsigned short* __restrict__ xb, const unsigned short* __restrict__ Bsrc,
             const float* __restrict__ b1, const int* __restrict__ cntp,
             const int* __restrict__ offp, const int* __restrict__ asgT,
             unsigned short* __restrict__ h) {
  GEMM_CORE(
    /*EPILOG_PRE*/ {
      float bcol[4];
      _Pragma("unroll")
      for (int j = 0; j < 4; ++j) bcol[j] = b1[e * DDIM + n0 + wc * 64 + j * 16 + r];
      _Pragma("unroll")
      for (int i = 0; i < 8; ++i) {
        _Pragma("unroll")
        for (int q = 0; q < 4; ++q) {
          int grow = m0 + wr * 128 + i * 16 + kc * 4 + q;  // C/D: row=(l>>4)*4+q, col=l&15
          if (grow < cnt) {
            size_t hrow = (size_t)(off + grow) * DDIM;
            _Pragma("unroll")
            for (int j = 0; j < 4; ++j) {
              int col = n0 + wc * 64 + j * 16 + r;
              h[hrow + col] = f2bf(gelu_exact(acc[i][j][q] + bcol[j]));
            }
          }
        }
      }
    },
    /*SRC_A_INIT*/ {
      int tok = asgT[off + rowc];
      srcA[i] = xb + (size_t)tok * DDIM + kc * 8;
    });
}

// ---------------- GEMM2: out[tok] += w * (h @ W2[e]^T + b2[e]) ----------------
__global__ __launch_bounds__(512, 2)
void gemm2_k(const unsigned short* __restrict__ hsrc, const unsigned short* __restrict__ Bsrc,
             const float* __restrict__ b2, const int* __restrict__ cntp,
             const int* __restrict__ offp, const int* __restrict__ asgT,
             const float* __restrict__ asgW, float* __restrict__ out) {
  GEMM_CORE(
    /*EPILOG_PRE*/ {
      float bcol[4];
      _Pragma("unroll")
      for (int j = 0; j < 4; ++j) bcol[j] = b2[e * DDIM + n0 + wc * 64 + j * 16 + r];
      _Pragma("unroll")
      for (int i = 0; i < 8; ++i) {
        _Pragma("unroll")
        for (int q = 0; q < 4; ++q) {
          int grow = m0 + wr * 128 + i * 16 + kc * 4 + q;
          if (grow < cnt) {
            int tok = asgT[off + grow];
            float wgt = asgW[off + grow];
            float* orow = out + (size_t)tok * DDIM;
            _Pragma("unroll")
            for (int j = 0; j < 4; ++j) {
              int col = n0 + wc * 64 + j * 16 + r;
              atomicAdd(&orow[col], wgt * (acc[i][j][q] + bcol[j]));
            }
          }
        }
      }
    },
    /*SRC_A_INIT*/ {
      srcA[i] = hsrc + (size_t)(off + rowc) * DDIM + kc * 8;
    });
}

// ---------------- launch ----------------
// ws layout (bytes):
//   0      cnt[8] padded x128B | 4096 off[8] | 8192 cur[8] padded
//   16384  tokE[NTOK] int32 (64KB) | +64K tokW float2 (128KB)
//   ...    asgT[2N] (128KB) | asgW[2N] (128KB)
//   1 MB   xb bf16 (32MB) | 33MB w1b (16MB) | 49MB w2b (16MB) | 65MB h (64MB)
extern "C" void kernel_launch(void* const* d_in, const int* in_sizes, int n_in,
                              void* d_out, int out_size, void* d_ws, size_t ws_size,
                              hipStream_t stream) {
  (void)in_sizes; (void)n_in; (void)ws_size;
  const float* x  = (const float*)d_in[0];
  const float* Wr = (const float*)d_in[1];
  const float* W1 = (const float*)d_in[2];
  const float* b1 = (const float*)d_in[3];
  const float* W2 = (const float*)d_in[4];
  const float* b2 = (const float*)d_in[5];
  float* out = (float*)d_out;

  char* ws = (char*)d_ws;
  int*    cnt  = (int*)(ws + 0);
  int*    off  = (int*)(ws + 4096);
  int*    cur  = (int*)(ws + 8192);
  int*    tokE = (int*)(ws + 16384);
  float2* tokW = (float2*)(ws + 16384 + 65536);
  int*    asgT = (int*)(ws + 16384 + 65536 + 131072);
  float*  asgW = (float*)(ws + 16384 + 65536 + 131072 + 131072);
  unsigned short* xb  = (unsigned short*)(ws + (size_t)(1u << 20));
  unsigned short* w1b = (unsigned short*)(ws + (size_t)33 * (1u << 20));
  unsigned short* w2b = (unsigned short*)(ws + (size_t)49 * (1u << 20));
  unsigned short* h   = (unsigned short*)(ws + (size_t)65 * (1u << 20));

  hipMemsetAsync(ws, 0, 16384, stream);                       // cnt + cur
  hipMemsetAsync(d_out, 0, (size_t)out_size * sizeof(float), stream);

  const int nW = NEXP * DDIM * DDIM;   // 8,388,608
  cast_k<<<(nW / 4) / 256, 256, 0, stream>>>(W1, w1b, nW / 4);
  cast_k<<<(nW / 4) / 256, 256, 0, stream>>>(W2, w2b, nW / 4);

  castx_router_k<<<NTOK, 256, 0, stream>>>(x, Wr, xb, tokE, tokW);
  hist_k<<<NTOK / 256, 256, 0, stream>>>(tokE, cnt);
  offsets_k<<<1, 64, 0, stream>>>(cnt, off);
  place_k<<<NTOK / 256, 256, 0, stream>>>(tokE, tokW, off, cur, asgT, asgW);

  dim3 ggrid(64, 4, NEXP);   // worst-case m-tiles of 256; blocks past cnt[e] exit
  gemm1_k<<<ggrid, 512, 0, stream>>>(xb, w1b, b1, cnt, off, asgT, h);
  gemm2_k<<<ggrid, 512, 0, stream>>>(h, w2b, b2, cnt, off, asgT, asgW, out);
}

// Round 8
// 682.536 us; speedup vs baseline: 1.1965x; 1.1965x over previous
//
#include <hip/hip_runtime.h>
#include <hip/hip_bf16.h>
#include <cstdint>
#include <cstddef>

#define NTOK 16384   // B*L = 4*4096
#define DDIM 1024
#define NEXP 8
#define NPAIR 64     // pair slot = lo*8+hi (lo<hi); <=28 nonzero
#define CPAD 32      // counter padding: 32 ints = 128B per counter

typedef __attribute__((ext_vector_type(8))) short bf16x8;
typedef __attribute__((ext_vector_type(4))) float f32x4;

__device__ __forceinline__ unsigned short f2bf(float f) {
  union { float f; unsigned u; } c; c.f = f;
  unsigned r = (c.u + 0x7FFFu + ((c.u >> 16) & 1u)) >> 16;  // RNE
  return (unsigned short)r;
}

__device__ __forceinline__ float gelu_exact(float v) {
  return 0.5f * v * (1.0f + erff(v * 0.70710678118654752440f));
}

// direct global->LDS async copy, 16B per lane. LDS dest must be linear
// (wave-uniform base + lane*16); source address is per-lane.
#define GL2LDS(gp, lp) __builtin_amdgcn_global_load_lds( \
    (__attribute__((address_space(1))) void*)(gp),       \
    (__attribute__((address_space(3))) void*)(lp), 16, 0, 0)

// ---------------- fused weight cast fp32 -> bf16 (W1 and W2 in one kernel) ----------------
__global__ void castw_k(const float* __restrict__ W1, const float* __restrict__ W2,
                        unsigned short* __restrict__ w1b, unsigned short* __restrict__ w2b) {
  const int H = 2 * 1024 * 1024;                 // float4 count per 8M-float matrix
  int i = blockIdx.x * blockDim.x + threadIdx.x; // 0 .. 4M-1
  const float4* s; unsigned short* d; int k;
  if (i < H) { s = (const float4*)W1; d = w1b; k = i; }
  else       { s = (const float4*)W2; d = w2b; k = i - H; }
  float4 a = s[k];
  union { unsigned short s4[4]; uint2 v; } o;
  o.s4[0] = f2bf(a.x); o.s4[1] = f2bf(a.y); o.s4[2] = f2bf(a.z); o.s4[3] = f2bf(a.w);
  ((uint2*)d)[k] = o.v;
}

// ---------------- fused x-cast + router: one block per token, NO atomics ----------------
// Emits pair id (lo*8+hi) and (w_lo, w_hi) renormalized top-2 weights.
__global__ __launch_bounds__(256)
void castx_router_k(const float* __restrict__ x, const float* __restrict__ Wr,
                    unsigned short* __restrict__ xb, int* __restrict__ tokP,
                    float2* __restrict__ tokW) {
  const int t = blockIdx.x;
  const int tid = threadIdx.x;
  const int w = tid >> 6, lane = tid & 63;

  float4 xv = ((const float4*)x)[(size_t)t * 256 + tid];   // coalesced 16B/thread
  union { unsigned short s4[4]; uint2 v; } o;
  o.s4[0] = f2bf(xv.x); o.s4[1] = f2bf(xv.y); o.s4[2] = f2bf(xv.z); o.s4[3] = f2bf(xv.w);
  ((uint2*)xb)[(size_t)t * 256 + tid] = o.v;

  const float4* Wr4 = (const float4*)Wr;                   // 32KB, L1-resident
  float p[NEXP];
#pragma unroll
  for (int e = 0; e < NEXP; ++e) {
    float4 wv = Wr4[e * 256 + tid];
    p[e] = xv.x * wv.x + xv.y * wv.y + xv.z * wv.z + xv.w * wv.w;
  }
#pragma unroll
  for (int e = 0; e < NEXP; ++e) {
    float v = p[e];
#pragma unroll
    for (int off = 32; off >= 1; off >>= 1) v += __shfl_xor(v, off, 64);
    p[e] = v;
  }
  __shared__ float red[4][NEXP];
  if (lane == 0) {
#pragma unroll
    for (int e = 0; e < NEXP; ++e) red[w][e] = p[e];
  }
  __syncthreads();
  if (tid == 0) {
    float s[NEXP];
#pragma unroll
    for (int e = 0; e < NEXP; ++e) s[e] = red[0][e] + red[1][e] + red[2][e] + red[3][e];
    int e1 = 0; float m1 = s[0];
#pragma unroll
    for (int e = 1; e < NEXP; ++e) if (s[e] > m1) { m1 = s[e]; e1 = e; }
    int e2 = -1; float m2 = -3.4e38f;
#pragma unroll
    for (int e = 0; e < NEXP; ++e) {
      if (e == e1) continue;
      if (s[e] > m2) { m2 = s[e]; e2 = e; }
    }
    float dd = expf(m2 - m1);                 // renormalized top-2 softmax
    float w1 = 1.f / (1.f + dd);              // weight of e1 (argmax)
    float w2 = dd / (1.f + dd);               // weight of e2
    int lo = e1 < e2 ? e1 : e2;
    int hi = e1 < e2 ? e2 : e1;
    float wlo = (e1 < e2) ? w1 : w2;
    float whi = (e1 < e2) ? w2 : w1;
    tokP[t] = lo * 8 + hi;
    tokW[t] = make_float2(wlo, whi);
  }
}

// ---------------- pair histogram: LDS-aggregated, <=64 atomics/block ----------------
__global__ __launch_bounds__(256)
void hist_k(const int* __restrict__ tokP, int* __restrict__ cnt) {
  __shared__ int bins[NPAIR];
  if (threadIdx.x < NPAIR) bins[threadIdx.x] = 0;
  __syncthreads();
  int t = blockIdx.x * 256 + threadIdx.x;
  atomicAdd(&bins[tokP[t]], 1);
  __syncthreads();
  if (threadIdx.x < NPAIR) {
    int c = bins[threadIdx.x];
    if (c) atomicAdd(&cnt[threadIdx.x * CPAD], c);
  }
}

// ---------------- offsets + (pid, mtile) work map ----------------
__global__ void offsets_k(const int* __restrict__ cnt, int* __restrict__ off,
                          int* __restrict__ map, int* __restrict__ nwork) {
  if (threadIdx.x == 0) {
    int a = 0, nw = 0;
    for (int s = 0; s < NPAIR; ++s) {
      off[s] = a;
      int c = cnt[s * CPAD];
      a += c;
      for (int mt = 0; mt * 128 < c; ++mt) map[nw++] = (s << 16) | mt;
    }
    nwork[0] = nw;   // <= 128 + 28 = 156
  }
}

// ---------------- placement: wave-aggregated slot alloc over 64 padded counters ----------------
__global__ __launch_bounds__(256)
void place_k(const int* __restrict__ tokP, const float2* __restrict__ tokW,
             const int* __restrict__ off, int* __restrict__ cur,
             int* __restrict__ asgT, float2* __restrict__ asgW2) {
  int t = blockIdx.x * 256 + threadIdx.x;
  int pid = tokP[t];
  int lane = threadIdx.x & 63;
  int slot = 0;
#pragma unroll 1
  for (int s = 0; s < NPAIR; ++s) {
    unsigned long long m = __ballot(pid == s);
    if (pid == s) {
      int leader = __ffsll((long long)m) - 1;
      int base = 0;
      if (lane == leader) base = atomicAdd(&cur[s * CPAD], (int)__popcll(m));
      base = __shfl(base, leader, 64);
      slot = base + (int)__popcll(m & ((1ull << lane) - 1ull));
    }
  }
  int p = off[pid] + slot;
  asgT[p] = t;
  asgW2[p] = tokW[t];
}

// ============== GEMM core: 128x128 tile, 4 waves, R4-proven 2-barrier loop ==============
// Fragment-major LDS (0 bank conflicts measured R4-R7): sub-block(g[,ks]) of 1KB holds
// 16 rows x 32 k; lane (kc*16+r)*16B -> gl2lds linear dest == conflict-free ds_read_b128.

// ---------------- GEMM1: h[row] = w_half * gelu(gather(x) @ [W1[lo];W1[hi]]^T + b1) ----------------
// Grouped by expert-pair; N = 2048 (two experts' outputs side by side); BK=32.
__global__ __launch_bounds__(256)
void gemm1_k(const unsigned short* __restrict__ xb, const unsigned short* __restrict__ w1b,
             const float* __restrict__ b1, const int* __restrict__ cntp,
             const int* __restrict__ offp, const int* __restrict__ map,
             const int* __restrict__ nwork, const int* __restrict__ asgT,
             const float2* __restrict__ asgW2, unsigned short* __restrict__ h) {
  if ((int)blockIdx.x >= nwork[0]) return;
  const int mp = map[blockIdx.x];
  const int pid = mp >> 16, mt = mp & 0xFFFF;
  const int cnt = cntp[pid * CPAD];
  const int off = offp[pid];
  const int m0 = mt * 128;
  const int n0 = blockIdx.y * 128;          // 0..2047
  const int half = n0 >> 10;
  const int e = half ? (pid & 7) : (pid >> 3);
  const int nc0 = n0 & 1023;

  __shared__ __align__(16) unsigned short As[2][4096];
  __shared__ __align__(16) unsigned short Bs[2][4096];

  const int tid = threadIdx.x;
  const int w = tid >> 6, lane = tid & 63;
  const int r = lane & 15, kc = lane >> 4;
  const int wr = w >> 1, wc = w & 1;

  const unsigned short* srcA[2];
  const unsigned short* srcB[2];
#pragma unroll
  for (int i = 0; i < 2; ++i) {
    int g = w + i * 4;
    int rowt = m0 + g * 16 + r;
    int rowc = (rowt < cnt) ? rowt : m0;      // clamp (m0 valid by map construction)
    int tok = asgT[off + rowc];
    srcA[i] = xb + (size_t)tok * DDIM + kc * 8;
    int coln = nc0 + g * 16 + r;
    srcB[i] = w1b + (size_t)e * DDIM * DDIM + (size_t)coln * DDIM + kc * 8;
  }

  f32x4 acc[4][4];
#pragma unroll
  for (int i = 0; i < 4; ++i)
#pragma unroll
    for (int j = 0; j < 4; ++j) acc[i][j] = (f32x4){0.f, 0.f, 0.f, 0.f};

  auto stage = [&](int buf, int k0) {
#pragma unroll
    for (int i = 0; i < 2; ++i) {
      int g = w + i * 4;
      GL2LDS(srcA[i] + k0, &As[buf][g * 512 + lane * 8]);
      GL2LDS(srcB[i] + k0, &Bs[buf][g * 512 + lane * 8]);
    }
  };

  stage(0, 0);
#pragma unroll 2
  for (int t = 0; t < 32; ++t) {              // K = 1024
    int buf = t & 1;
    __syncthreads();                          // drains stage (vmcnt) + read fence
    if (t + 1 < 32) stage(buf ^ 1, (t + 1) * 32);
    bf16x8 af[4], bv[4];
#pragma unroll
    for (int i = 0; i < 4; ++i) {
      af[i] = *(const bf16x8*)&As[buf][(wr * 4 + i) * 512 + lane * 8];
      bv[i] = *(const bf16x8*)&Bs[buf][(wc * 4 + i) * 512 + lane * 8];
    }
#pragma unroll
    for (int i = 0; i < 4; ++i)
#pragma unroll
      for (int j = 0; j < 4; ++j)
        acc[i][j] = __builtin_amdgcn_mfma_f32_16x16x32_bf16(af[i], bv[j], acc[i][j], 0, 0, 0);
  }

  float bcol[4];
#pragma unroll
  for (int j = 0; j < 4; ++j) bcol[j] = b1[e * DDIM + nc0 + wc * 64 + j * 16 + r];
#pragma unroll
  for (int i = 0; i < 4; ++i) {
#pragma unroll
    for (int q = 0; q < 4; ++q) {
      int grow = m0 + wr * 64 + i * 16 + kc * 4 + q;   // C/D: row=(l>>4)*4+q, col=l&15
      if (grow < cnt) {
        float2 wv = asgW2[off + grow];
        float sc = half ? wv.y : wv.x;
        size_t hrow = (size_t)(off + grow) * 2048;
#pragma unroll
        for (int j = 0; j < 4; ++j) {
          int col = n0 + wc * 64 + j * 16 + r;
          h[hrow + col] = f2bf(sc * gelu_exact(acc[i][j][q] + bcol[j]));
        }
      }
    }
  }
}

// ---------------- GEMM2: out[tok] = h_row(2048) @ [W2[lo];W2[hi]]^T + wlo*b2[lo]+whi*b2[hi] ----------------
// K = 2048 (stacked), BK=64 (32 steps). Direct stores — every out row produced exactly once.
__global__ __launch_bounds__(256)
void gemm2_k(const unsigned short* __restrict__ hsrc, const unsigned short* __restrict__ w2b,
             const float* __restrict__ b2, const int* __restrict__ cntp,
             const int* __restrict__ offp, const int* __restrict__ map,
             const int* __restrict__ nwork, const int* __restrict__ asgT,
             const float2* __restrict__ asgW2, float* __restrict__ out) {
  if ((int)blockIdx.x >= nwork[0]) return;
  const int mp = map[blockIdx.x];
  const int pid = mp >> 16, mt = mp & 0xFFFF;
  const int cnt = cntp[pid * CPAD];
  const int off = offp[pid];
  const int m0 = mt * 128;
  const int n0 = blockIdx.y * 128;          // 0..1023
  const int elo = pid >> 3, ehi = pid & 7;

  __shared__ __align__(16) unsigned short As[2][8192];   // 128 x 64
  __shared__ __align__(16) unsigned short Bs[2][8192];

  const int tid = threadIdx.x;
  const int w = tid >> 6, lane = tid & 63;
  const int r = lane & 15, kc = lane >> 4;
  const int wr = w >> 1, wc = w & 1;

  const unsigned short* srcA[2];
  const unsigned short* srcBlo[2];
  const unsigned short* srcBhi[2];
#pragma unroll
  for (int i = 0; i < 2; ++i) {
    int g = w + i * 4;
    int rowt = m0 + g * 16 + r;
    int rowc = (rowt < cnt) ? rowt : m0;
    srcA[i] = hsrc + (size_t)(off + rowc) * 2048 + kc * 8;   // h rows contiguous in-group
    int coln = n0 + g * 16 + r;
    srcBlo[i] = w2b + (size_t)elo * DDIM * DDIM + (size_t)coln * DDIM + kc * 8;
    srcBhi[i] = w2b + (size_t)ehi * DDIM * DDIM + (size_t)coln * DDIM + kc * 8;
  }

  f32x4 acc[4][4];
#pragma unroll
  for (int i = 0; i < 4; ++i)
#pragma unroll
    for (int j = 0; j < 4; ++j) acc[i][j] = (f32x4){0.f, 0.f, 0.f, 0.f};

  // k0 is a multiple of 64; half boundary (1024) is too, so one base per stage call.
  auto stage = [&](int buf, int k0) {
    int kb = k0 & 1023;
#pragma unroll
    for (int i = 0; i < 2; ++i) {
      int g = w + i * 4;
      const unsigned short* pb = (k0 & 1024) ? srcBhi[i] : srcBlo[i];
#pragma unroll
      for (int ks = 0; ks < 2; ++ks) {
        GL2LDS(srcA[i] + k0 + ks * 32, &As[buf][(g * 2 + ks) * 512 + lane * 8]);
        GL2LDS(pb + kb + ks * 32,      &Bs[buf][(g * 2 + ks) * 512 + lane * 8]);
      }
    }
  };

  stage(0, 0);
  for (int t = 0; t < 32; ++t) {              // K = 2048 = 32 x 64
    int buf = t & 1;
    __syncthreads();
    if (t + 1 < 32) stage(buf ^ 1, (t + 1) * 64);
#pragma unroll
    for (int ks = 0; ks < 2; ++ks) {
      bf16x8 af[4], bv[4];
#pragma unroll
      for (int i = 0; i < 4; ++i) {
        af[i] = *(const bf16x8*)&As[buf][((wr * 4 + i) * 2 + ks) * 512 + lane * 8];
        bv[i] = *(const bf16x8*)&Bs[buf][((wc * 4 + i) * 2 + ks) * 512 + lane * 8];
      }
#pragma unroll
      for (int i = 0; i < 4; ++i)
#pragma unroll
        for (int j = 0; j < 4; ++j)
          acc[i][j] = __builtin_amdgcn_mfma_f32_16x16x32_bf16(af[i], bv[j], acc[i][j], 0, 0, 0);
    }
  }

  float b2lo[4], b2hi[4];
#pragma unroll
  for (int j = 0; j < 4; ++j) {
    int col = n0 + wc * 64 + j * 16 + r;
    b2lo[j] = b2[elo * DDIM + col];
    b2hi[j] = b2[ehi * DDIM + col];
  }
#pragma unroll
  for (int i = 0; i < 4; ++i) {
#pragma unroll
    for (int q = 0; q < 4; ++q) {
      int grow = m0 + wr * 64 + i * 16 + kc * 4 + q;
      if (grow < cnt) {
        int tok = asgT[off + grow];
        float2 wv = asgW2[off + grow];
        float* orow = out + (size_t)tok * DDIM;
#pragma unroll
        for (int j = 0; j < 4; ++j) {
          int col = n0 + wc * 64 + j * 16 + r;
          orow[col] = acc[i][j][q] + wv.x * b2lo[j] + wv.y * b2hi[j];   // direct store
        }
      }
    }
  }
}

// ---------------- launch ----------------
// ws layout (bytes):
//   0      cnt[64] padded x128B (8KB) | 8192 cur[64] padded (8KB)
//   16384  off[64] int | 16640 nwork | 16648 map[160] int
//   32768  tokP[NTOK] int (64KB) | 98304 tokW[NTOK] float2 (128KB)
//   229376 asgT[NTOK] int (64KB) | 294912 asgW2[NTOK] float2 (128KB)
//   1 MB   xb bf16 (32MB) | 33MB w1b (16MB) | 49MB w2b (16MB)
//   65MB   h bf16 [NTOK][2048] (64MB)  -> total 129MB
extern "C" void kernel_launch(void* const* d_in, const int* in_sizes, int n_in,
                              void* d_out, int out_size, void* d_ws, size_t ws_size,
                              hipStream_t stream) {
  (void)in_sizes; (void)n_in; (void)ws_size; (void)out_size;
  const float* x  = (const float*)d_in[0];
  const float* Wr = (const float*)d_in[1];
  const float* W1 = (const float*)d_in[2];
  const float* b1 = (const float*)d_in[3];
  const float* W2 = (const float*)d_in[4];
  const float* b2 = (const float*)d_in[5];
  float* out = (float*)d_out;

  char* ws = (char*)d_ws;
  int*    cnt   = (int*)(ws + 0);
  int*    cur   = (int*)(ws + 8192);
  int*    off   = (int*)(ws + 16384);
  int*    nwork = (int*)(ws + 16640);
  int*    map   = (int*)(ws + 16648);
  int*    tokP  = (int*)(ws + 32768);
  float2* tokW  = (float2*)(ws + 98304);
  int*    asgT  = (int*)(ws + 229376);
  float2* asgW2 = (float2*)(ws + 294912);
  unsigned short* xb  = (unsigned short*)(ws + (size_t)(1u << 20));
  unsigned short* w1b = (unsigned short*)(ws + (size_t)33 * (1u << 20));
  unsigned short* w2b = (unsigned short*)(ws + (size_t)49 * (1u << 20));
  unsigned short* h   = (unsigned short*)(ws + (size_t)65 * (1u << 20));

  hipMemsetAsync(ws, 0, 16384, stream);                       // cnt + cur

  castw_k<<<16384, 256, 0, stream>>>(W1, W2, w1b, w2b);       // 4M float4
  castx_router_k<<<NTOK, 256, 0, stream>>>(x, Wr, xb, tokP, tokW);
  hist_k<<<NTOK / 256, 256, 0, stream>>>(tokP, cnt);
  offsets_k<<<1, 64, 0, stream>>>(cnt, off, map, nwork);
  place_k<<<NTOK / 256, 256, 0, stream>>>(tokP, tokW, off, cur, asgT, asgW2);

  // nwork <= 156; blocks with bx >= nwork exit immediately
  dim3 g1(160, 16);   // N = 2048
  dim3 g2(160, 8);    // N = 1024
  gemm1_k<<<g1, 256, 0, stream>>>(xb, w1b, b1, cnt, off, map, nwork, asgT, asgW2, h);
  gemm2_k<<<g2, 256, 0, stream>>>(h, w2b, b2, cnt, off, map, nwork, asgT, asgW2, out);
}